// Round 11
// baseline (956.421 us; speedup 1.0000x reference)
//
#include <hip/hip_runtime.h>
#include <math.h>

#define NPTS 4096
#define NB 16
#define NS 1024
#define KNB 32
#define CPTS 64

// ---- ws byte layout ----
#define FLAG_OFF_B  0          // 16 x u32 flags
#define CNT_OFF_B   64         // u32 work counter
#define PUBC_OFF_B  128        // fp32 pubC[16][1024][3]
#define WFRAG_ELEMS 18432
#define NGROUPS     2048       // 16384 queries / 8 per group

typedef __attribute__((ext_vector_type(8))) short short8;
typedef __attribute__((ext_vector_type(4))) float f32x4;

__device__ __forceinline__ short f2bf(float f) {   // RNE fp32->bf16
  unsigned u = __float_as_uint(f);
  unsigned r = (u + 0x7fffu + ((u >> 16) & 1u)) >> 16;
  return (short)r;
}

// ---------------- DPP helpers ----------------
template <int CTRL>
__device__ __forceinline__ int dppmov(int cur) {
  return __builtin_amdgcn_update_dpp(cur, cur, CTRL, 0xF, 0xF, false);
}
template <int CTRL>
__device__ __forceinline__ void dpp_min_u64(unsigned& hi, unsigned& lo) {
  unsigned nhi = (unsigned)dppmov<CTRL>((int)hi);
  unsigned nlo = (unsigned)dppmov<CTRL>((int)lo);
  bool lt = (nhi < hi) || (nhi == hi && nlo < lo);
  hi = lt ? nhi : hi;
  lo = lt ? nlo : lo;
}
template <int CTRL>
__device__ __forceinline__ void dpp_max_u64(unsigned& hi, unsigned& lo) {
  unsigned nhi = (unsigned)dppmov<CTRL>((int)hi);
  unsigned nlo = (unsigned)dppmov<CTRL>((int)lo);
  bool gt = (nhi > hi) || (nhi == hi && nlo > lo);
  hi = gt ? nhi : hi;
  lo = gt ? nlo : lo;
}

#define XSTR 104
__global__ __launch_bounds__(512, 2) void fused_kernel(
    const float* __restrict__ xyz, const float* __restrict__ points,
    const float* __restrict__ w0, const float* __restrict__ cb0, const float* __restrict__ g0,
    const float* __restrict__ b0, const float* __restrict__ m0, const float* __restrict__ v0,
    const float* __restrict__ w1, const float* __restrict__ cb1, const float* __restrict__ g1,
    const float* __restrict__ b1, const float* __restrict__ m1, const float* __restrict__ v1,
    const float* __restrict__ w2, const float* __restrict__ cb2, const float* __restrict__ g2,
    const float* __restrict__ b2, const float* __restrict__ m2, const float* __restrict__ v2,
    char* __restrict__ wsb, float* __restrict__ newxyz, float* __restrict__ outp) {
  struct FpsSh {
    float4 sxyz4[NPTS];                       // 64 KB
    float4 centL[NS];                         // 16 KB
    unsigned long long part[2][4];
  };
  struct WorkerSh {
    short Wlds[WFRAG_ELEMS];                  // 36 KB
    union {
      unsigned long long slist[2][4096];      // 64 KB (knn phase)
      short X[8][32 * XSTR];                  // 52 KB (mlp phase)
    } u;
    unsigned long long wl[2][128];
    int nnL[8][KNB];
    float biasL[256];
    float pubq[8][3];
    unsigned gshare;
  };
  __shared__ union { FpsSh f; WorkerSh w; } sh;

  const int t = threadIdx.x;
  const int lane = t & 63;
  const int wave = t >> 6;
  unsigned* flagp = (unsigned*)(wsb + FLAG_OFF_B);
  unsigned* cntp  = (unsigned*)(wsb + CNT_OFF_B);
  float* pubC = (float*)(wsb + PUBC_OFF_B);

  if (blockIdx.x < NB) {
    // ================= FPS: waves 0-3 only (1 wave/SIMD); waves 4-7 match barriers ==========
    const int b = blockIdx.x;
    const float* xb = xyz + (size_t)b * NPTS * 3;
    float* outb = newxyz + (size_t)b * NS * 3;

    for (int i = t; i < NPTS; i += 512)
      sh.f.sxyz4[i] = make_float4(xb[i * 3 + 0], xb[i * 3 + 1], xb[i * 3 + 2], 0.f);

    if (wave < 4) {
      float px[16], py[16], pz[16], dist[16];
#pragma unroll
      for (int j = 0; j < 16; ++j) {
        int n = t + 256 * j;
        px[j] = xb[n * 3 + 0];
        py[j] = xb[n * 3 + 1];
        pz[j] = xb[n * 3 + 2];
        dist[j] = 1e10f;
      }
      __syncthreads();                                    // barrier #0
      float cx = sh.f.sxyz4[0].x, cy = sh.f.sxyz4[0].y, cz = sh.f.sxyz4[0].z;
      if (t == 0) sh.f.centL[0] = sh.f.sxyz4[0];

      for (int it = 1; it < NS; ++it) {
        const int buf = it & 1;
        float dm[16];
#pragma unroll
        for (int j = 0; j < 16; ++j) {
          // exact replication of sum((xyz - c)**2, -1): no FMA contraction
          float dx = __fsub_rn(px[j], cx);
          float dy = __fsub_rn(py[j], cy);
          float dz = __fsub_rn(pz[j], cz);
          float d  = __fadd_rn(__fadd_rn(__fmul_rn(dx, dx), __fmul_rn(dy, dy)), __fmul_rn(dz, dz));
          float v  = fminf(dist[j], d);
          dist[j] = v;
          dm[j] = v;
        }
        // lane-local max: depth-4 tree
        float t8[8], t4a[4];
#pragma unroll
        for (int k = 0; k < 8; ++k) t8[k] = fmaxf(dm[k], dm[k + 8]);
#pragma unroll
        for (int k = 0; k < 4; ++k) t4a[k] = fmaxf(t8[k], t8[k + 4]);
        float M = fmaxf(fmaxf(t4a[0], t4a[1]), fmaxf(t4a[2], t4a[3]));
        // lane-local min idx achieving M: depth-5 tree
        unsigned c8[8], c4a[4];
#pragma unroll
        for (int k = 0; k < 8; ++k) {
          unsigned a = (dm[k] == M)     ? (unsigned)(t + 256 * k)       : 0xFFFFFFFFu;
          unsigned bq = (dm[k + 8] == M) ? (unsigned)(t + 256 * (k + 8)) : 0xFFFFFFFFu;
          c8[k] = a < bq ? a : bq;
        }
#pragma unroll
        for (int k = 0; k < 4; ++k) c4a[k] = c8[k] < c8[k + 4] ? c8[k] : c8[k + 4];
        unsigned i2a = c4a[0] < c4a[2] ? c4a[0] : c4a[2];
        unsigned i2b = c4a[1] < c4a[3] ? c4a[1] : c4a[3];
        unsigned il = i2a < i2b ? i2a : i2b;
        // wave reduce: u64 (Mbits, ~il) max -> (max val, min idx), result in lane 63
        unsigned hi = __float_as_uint(M), lo = ~il;
        dpp_max_u64<0xB1>(hi, lo);
        dpp_max_u64<0x4E>(hi, lo);
        dpp_max_u64<0x141>(hi, lo);
        dpp_max_u64<0x140>(hi, lo);
        dpp_max_u64<0x142>(hi, lo);
        dpp_max_u64<0x143>(hi, lo);
        if (lane == 63) sh.f.part[buf][wave] = ((unsigned long long)hi << 32) | lo;
        __syncthreads();                                  // barriers #1..#1023
        // merge 4 partials: slot read + 2-stage quad DPP u64 max (every lane gets winner)
        unsigned long long k0 = sh.f.part[buf][lane & 3];
        unsigned khi = (unsigned)(k0 >> 32), klo = (unsigned)k0;
        dpp_max_u64<0xB1>(khi, klo);
        dpp_max_u64<0x4E>(khi, klo);
        int bi = (int)(~klo) & 4095;
        float4 c4v = sh.f.sxyz4[bi];
        cx = c4v.x; cy = c4v.y; cz = c4v.z;
        if (t == 0) sh.f.centL[it] = c4v;
        // publish: release flag for PREVIOUS chunk (stores already drained), then store chunk
        if ((it & 31) == 31 && wave == 0) {
          if (lane == 0)
            __hip_atomic_store(&flagp[b], (unsigned)(it - 31), __ATOMIC_RELEASE, __HIP_MEMORY_SCOPE_AGENT);
          if (lane < 32) {
            int ci = it - 31 + lane;
            float4 cc = sh.f.centL[ci];
            float* dst = pubC + ((size_t)b * NS + ci) * 3;
            __hip_atomic_store(dst + 0, cc.x, __ATOMIC_RELAXED, __HIP_MEMORY_SCOPE_AGENT);
            __hip_atomic_store(dst + 1, cc.y, __ATOMIC_RELAXED, __HIP_MEMORY_SCOPE_AGENT);
            __hip_atomic_store(dst + 2, cc.z, __ATOMIC_RELAXED, __HIP_MEMORY_SCOPE_AGENT);
          }
        }
      }
      if (t == 0)
        __hip_atomic_store(&flagp[b], (unsigned)NS, __ATOMIC_RELEASE, __HIP_MEMORY_SCOPE_AGENT);
      __syncthreads();                                    // barrier #1024
    } else {
      // idle waves: match FPS barrier count exactly (1 + 1023 + 1)
      __syncthreads();                                    // #0
      for (int it = 1; it < NS; ++it) __syncthreads();    // #1..#1023
      __syncthreads();                                    // #1024
    }
    const float* cf = (const float*)sh.f.centL;
    for (int i = t; i < NS * 3; i += 512) {
      int p = i / 3, c = i - p * 3;
      outb[i] = cf[p * 4 + c];
    }
  }

  // ================= worker phase (worker blocks immediately; FPS blocks after FPS) =========
  __syncthreads();
  // compute BN-folded bf16 weight fragments + biases directly into LDS (in wait shadow)
  for (int i = t; i < WFRAG_ELEMS; i += 512) {
    int g = i >> 9, ln = (i >> 3) & 63, j = i & 7;
    int l, nt, s;
    if (g < 12)      { l = 0; nt = g / 3;  s = g % 3; }
    else if (g < 20) { l = 1; int gg = g - 12; nt = gg >> 1; s = gg & 1; }
    else             { l = 2; int gg = g - 20; nt = gg >> 1; s = gg & 1; }
    int n = nt * 16 + (ln & 15);
    int k = s * 32 + ((ln >> 4) << 3) + j;
    float val = 0.f;
    if (l == 0) { if (k < 67) val = w0[n * 67 + k] * (g0[n] / sqrtf(v0[n] + 1e-5f)); }
    else if (l == 1) { val = w1[n * 64 + k] * (g1[n] / sqrtf(v1[n] + 1e-5f)); }
    else { val = w2[n * 64 + k] * (g2[n] / sqrtf(v2[n] + 1e-5f)); }
    sh.w.Wlds[i] = f2bf(val);
  }
  if (t < 256) {
    int o = t;
    float bv;
    if (o < 64)       { float sc = g0[o] / sqrtf(v0[o] + 1e-5f); bv = (cb0[o] - m0[o]) * sc + b0[o]; }
    else if (o < 128) { int c = o - 64;  float sc = g1[c] / sqrtf(v1[c] + 1e-5f); bv = (cb1[c] - m1[c]) * sc + b1[c]; }
    else              { int c = o - 128; float sc = g2[c] / sqrtf(v2[c] + 1e-5f); bv = (cb2[c] - m2[c]) * sc + b2[c]; }
    sh.w.biasL[o] = bv;
  }
  const int team = t >> 8, tt = t & 255;

  for (;;) {
    __syncthreads();                              // LDS reuse + gshare WAR
    if (t == 0) sh.w.gshare = atomicAdd(cntp, 1u);
    __syncthreads();
    unsigned g = sh.w.gshare;
    if (g >= NGROUPS) break;
    const int b = (int)(g & 15u);
    const int s0 = (int)(g >> 4) << 3;

    if (t == 0) {
      unsigned need = (unsigned)(s0 + 8);
      for (;;) {
        unsigned f = __hip_atomic_load(&flagp[b], __ATOMIC_ACQUIRE, __HIP_MEMORY_SCOPE_AGENT);
        if (f >= need) break;
        __builtin_amdgcn_s_sleep(8);
      }
    }
    __syncthreads();
    if (t < 24)
      sh.w.pubq[t / 3][t % 3] = __hip_atomic_load(
          &pubC[((size_t)b * NS + s0 + t / 3) * 3 + (t % 3)],
          __ATOMIC_RELAXED, __HIP_MEMORY_SCOPE_AGENT);
    __syncthreads();

    const float* xb = xyz + (size_t)b * NPTS * 3;

    // ---- knn: 2 teams x 4 sequential queries (verified algorithm) ----
    for (int sub = 0; sub < 4; ++sub) {
      const int qi = team * 4 + sub;
      float qx = sh.w.pubq[qi][0], qy = sh.w.pubq[qi][1], qz = sh.w.pubq[qi][2];
      float s2 = __fadd_rn(__fadd_rn(__fmul_rn(qx, qx), __fmul_rn(qy, qy)), __fmul_rn(qz, qz));
      unsigned long long key[16];
#pragma unroll
      for (int j = 0; j < 16; ++j) {
        int n = tt + 256 * j;
        float px = xb[n * 3], py = xb[n * 3 + 1], pz = xb[n * 3 + 2];
        float n2 = __fadd_rn(__fadd_rn(__fmul_rn(px, px), __fmul_rn(py, py)), __fmul_rn(pz, pz));
        float dt = __fadd_rn(__fadd_rn(__fmul_rn(qx, px), __fmul_rn(qy, py)), __fmul_rn(qz, pz));
        float d  = __fadd_rn(__fsub_rn(s2, __fmul_rn(2.0f, dt)), n2);
        unsigned u = __float_as_uint(d);
        u ^= (0x80000000u | (unsigned)((int)u >> 31));   // monotone float->uint
        key[j] = ((unsigned long long)u << 32) | (unsigned)n;
      }
      // per-thread Batcher odd-even mergesort of 16 keys (ascending)
#pragma unroll
      for (int p = 1; p < 16; p <<= 1) {
#pragma unroll
        for (int k = p; k >= 1; k >>= 1) {
#pragma unroll
          for (int j = k % p; j + k < 16; j += 2 * k) {
#pragma unroll
            for (int i = 0; i < k; ++i) {
              if (i + j + k < 16 && (i + j) / (2 * p) == (i + j + k) / (2 * p)) {
                unsigned long long ka = key[i + j], kb = key[i + j + k];
                unsigned long long mn = ka < kb ? ka : kb;
                unsigned long long mx = ka < kb ? kb : ka;
                key[i + j] = mn; key[i + j + k] = mx;
              }
            }
          }
        }
      }
#pragma unroll
      for (int i = 0; i < 16; ++i) sh.w.u.slist[team][i * 256 + tt] = key[i];

      // per-wave top-32 via head-pointer tournament
      unsigned long long head = key[0];
      unsigned long long nxt  = key[1];
      unsigned p = 1;
      for (int r = 0; r < KNB; ++r) {
        unsigned hi = (unsigned)(head >> 32), lo = (unsigned)head;
        dpp_min_u64<0xB1>(hi, lo);
        dpp_min_u64<0x4E>(hi, lo);
        dpp_min_u64<0x141>(hi, lo);
        dpp_min_u64<0x140>(hi, lo);
        dpp_min_u64<0x142>(hi, lo);
        dpp_min_u64<0x143>(hi, lo);
        unsigned whi = (unsigned)__builtin_amdgcn_readlane((int)hi, 63);
        unsigned wlo = (unsigned)__builtin_amdgcn_readlane((int)lo, 63);
        unsigned long long wkey = ((unsigned long long)whi << 32) | wlo;
        if ((tt & 63) == 0) sh.w.wl[team][(tt >> 6) * 32 + r] = wkey;
        if (head == wkey) {
          head = (p < 16) ? nxt : 0xFFFFFFFFFFFFFFFFull;
          unsigned pn = p + 1;
          nxt = sh.w.u.slist[team][(pn < 16 ? pn : 15) * 256 + tt];
          p = pn;
        }
      }
      __syncthreads();
      if (tt < 128) {                    // rank-merge (keys unique)
        unsigned long long mykey = sh.w.wl[team][tt];
        int gr = 0;
#pragma unroll 8
        for (int i = 0; i < 128; ++i) gr += (sh.w.wl[team][i] < mykey) ? 1 : 0;
        if (gr < KNB) sh.w.nnL[qi][gr] = (int)(mykey & 0xFFFFFFFFull);
      }
      __syncthreads();
    }

    // ---- mlp: 8 waves x 1 query (verified MFMA path) ----
    {
      const int qi = wave;
      const int s = s0 + qi;
      float qx = sh.w.pubq[qi][0], qy = sh.w.pubq[qi][1], qz = sh.w.pubq[qi][2];
      const float* pb = points + (size_t)b * NPTS * CPTS;
      const float* bias = sh.w.biasL;
      short* X = sh.w.u.X[qi];

      {
        int r = lane & 31, half = lane >> 5;
        int idx = sh.w.nnL[qi][r];
        const float* prow = pb + (size_t)idx * CPTS;
#pragma unroll
        for (int i = 0; i < 48; ++i) {
          int c = half * 48 + i;
          float v;
          if (c < 3) {
            float qc = (c == 0) ? qx : ((c == 1) ? qy : qz);
            v = __fsub_rn(xb[idx * 3 + c], qc);
          } else if (c < 67) {
            v = prow[c - 3];
          } else {
            v = 0.f;
          }
          X[r * XSTR + c] = f2bf(v);
        }
      }

      const int ml = lane & 15, quad = lane >> 4;
      const short8* Wf = (const short8*)sh.w.Wlds;

      // layer 0: M32 K96 N64
      short8 a0[2][3];
#pragma unroll
      for (int m2 = 0; m2 < 2; ++m2)
#pragma unroll
        for (int s3 = 0; s3 < 3; ++s3)
          a0[m2][s3] = *(const short8*)&X[(m2 * 16 + ml) * XSTR + s3 * 32 + quad * 8];
      f32x4 acc0[2][4];
#pragma unroll
      for (int m2 = 0; m2 < 2; ++m2)
#pragma unroll
        for (int nt = 0; nt < 4; ++nt) {
          f32x4 c = {0.f, 0.f, 0.f, 0.f};
#pragma unroll
          for (int s3 = 0; s3 < 3; ++s3)
            c = __builtin_amdgcn_mfma_f32_16x16x32_bf16(a0[m2][s3], Wf[(nt * 3 + s3) * 64 + lane], c, 0, 0, 0);
          acc0[m2][nt] = c;
        }
#pragma unroll
      for (int m2 = 0; m2 < 2; ++m2)
#pragma unroll
        for (int nt = 0; nt < 4; ++nt) {
          int ch = nt * 16 + ml;
          float bv = bias[ch];
#pragma unroll
          for (int r4 = 0; r4 < 4; ++r4) {
            float y = fmaxf(acc0[m2][nt][r4] + bv, 0.f);
            int m = quad * 4 + r4;
            int sK = ch >> 5, qq = (ch >> 3) & 3, jj = ch & 7;
            X[((m2 * 2 + sK) * 64 + qq * 16 + m) * 8 + jj] = f2bf(y);
          }
        }

      // layer 1: M32 K64 N64
      short8 a1[2][2];
#pragma unroll
      for (int m2 = 0; m2 < 2; ++m2)
#pragma unroll
        for (int sK = 0; sK < 2; ++sK)
          a1[m2][sK] = *(const short8*)&X[((m2 * 2 + sK) * 64 + lane) * 8];
      f32x4 acc1[2][4];
#pragma unroll
      for (int m2 = 0; m2 < 2; ++m2)
#pragma unroll
        for (int nt = 0; nt < 4; ++nt) {
          f32x4 c = {0.f, 0.f, 0.f, 0.f};
#pragma unroll
          for (int sK = 0; sK < 2; ++sK)
            c = __builtin_amdgcn_mfma_f32_16x16x32_bf16(a1[m2][sK], Wf[(12 + nt * 2 + sK) * 64 + lane], c, 0, 0, 0);
          acc1[m2][nt] = c;
        }
#pragma unroll
      for (int m2 = 0; m2 < 2; ++m2)
#pragma unroll
        for (int nt = 0; nt < 4; ++nt) {
          int ch = nt * 16 + ml;
          float bv = bias[64 + ch];
#pragma unroll
          for (int r4 = 0; r4 < 4; ++r4) {
            float y = fmaxf(acc1[m2][nt][r4] + bv, 0.f);
            int m = quad * 4 + r4;
            int sK = ch >> 5, qq = (ch >> 3) & 3, jj = ch & 7;
            X[((m2 * 2 + sK) * 64 + qq * 16 + m) * 8 + jj] = f2bf(y);
          }
        }

      // layer 2: M32 K64 N128 + maxpool
      short8 a2[2][2];
#pragma unroll
      for (int m2 = 0; m2 < 2; ++m2)
#pragma unroll
        for (int sK = 0; sK < 2; ++sK)
          a2[m2][sK] = *(const short8*)&X[((m2 * 2 + sK) * 64 + lane) * 8];
#pragma unroll
      for (int nt = 0; nt < 8; ++nt) {
        f32x4 c0 = {0.f, 0.f, 0.f, 0.f}, c1 = {0.f, 0.f, 0.f, 0.f};
        short8 w0f = Wf[(20 + nt * 2 + 0) * 64 + lane];
        short8 w1f = Wf[(20 + nt * 2 + 1) * 64 + lane];
        c0 = __builtin_amdgcn_mfma_f32_16x16x32_bf16(a2[0][0], w0f, c0, 0, 0, 0);
        c0 = __builtin_amdgcn_mfma_f32_16x16x32_bf16(a2[0][1], w1f, c0, 0, 0, 0);
        c1 = __builtin_amdgcn_mfma_f32_16x16x32_bf16(a2[1][0], w0f, c1, 0, 0, 0);
        c1 = __builtin_amdgcn_mfma_f32_16x16x32_bf16(a2[1][1], w1f, c1, 0, 0, 0);
        float bv = bias[128 + nt * 16 + ml];
        float m = -1.f;
#pragma unroll
        for (int r4 = 0; r4 < 4; ++r4) {
          m = fmaxf(m, fmaxf(c0[r4] + bv, 0.f));
          m = fmaxf(m, fmaxf(c1[r4] + bv, 0.f));
        }
        m = fmaxf(m, __shfl_xor(m, 16, 64));
        m = fmaxf(m, __shfl_xor(m, 32, 64));
        if (lane < 16) outp[((size_t)b * 128 + nt * 16 + lane) * NS + s] = m;
      }
    }
  }
}

extern "C" void kernel_launch(void* const* d_in, const int* in_sizes, int n_in,
                              void* d_out, int out_size, void* d_ws, size_t ws_size,
                              hipStream_t stream) {
  const float* xyz    = (const float*)d_in[0];
  const float* points = (const float*)d_in[1];
  const float* w0  = (const float*)d_in[2];
  const float* cb0 = (const float*)d_in[3];
  const float* g0  = (const float*)d_in[4];
  const float* b0  = (const float*)d_in[5];
  const float* m0  = (const float*)d_in[6];
  const float* v0  = (const float*)d_in[7];
  const float* w1  = (const float*)d_in[8];
  const float* cb1 = (const float*)d_in[9];
  const float* g1  = (const float*)d_in[10];
  const float* b1  = (const float*)d_in[11];
  const float* m1  = (const float*)d_in[12];
  const float* v1  = (const float*)d_in[13];
  const float* w2  = (const float*)d_in[14];
  const float* cb2 = (const float*)d_in[15];
  const float* g2  = (const float*)d_in[16];
  const float* b2  = (const float*)d_in[17];
  const float* m2  = (const float*)d_in[18];
  const float* v2  = (const float*)d_in[19];

  char*  wsb    = (char*)d_ws;
  float* newxyz = (float*)d_out;                       // output 0: [16,1024,3]
  float* outp   = (float*)d_out + (size_t)NB * NS * 3; // output 1: [16,128,1024]

  hipMemsetAsync(wsb, 0, 128, stream);   // flags + counter
  fused_kernel<<<256, 512, 0, stream>>>(
      xyz, points, w0, cb0, g0, b0, m0, v0, w1, cb1, g1, b1, m1, v1,
      w2, cb2, g2, b2, m2, v2, wsb, newxyz, outp);
}

// Round 12
// 908.403 us; speedup vs baseline: 1.0529x; 1.0529x over previous
//
#include <hip/hip_runtime.h>
#include <math.h>

#define NPTS 4096
#define NB 16
#define NS 1024
#define KNB 32
#define CPTS 64

// ---- ws byte layout ----
#define FLAG_OFF_B  0          // 16 x u32 flags
#define CNT_OFF_B   64         // u32 work counter
#define PUBC_OFF_B  128        // fp32 pubC[16][1024][3]
#define WFRAG_ELEMS 18432
#define NGROUPS     2048       // 16384 queries / 8 per group

typedef __attribute__((ext_vector_type(8))) short short8;
typedef __attribute__((ext_vector_type(4))) float f32x4;

__device__ __forceinline__ short f2bf(float f) {   // RNE fp32->bf16
  unsigned u = __float_as_uint(f);
  unsigned r = (u + 0x7fffu + ((u >> 16) & 1u)) >> 16;
  return (short)r;
}

// ---------------- DPP helpers ----------------
template <int CTRL>
__device__ __forceinline__ int dppmov(int cur) {
  return __builtin_amdgcn_update_dpp(cur, cur, CTRL, 0xF, 0xF, false);
}
template <int CTRL>
__device__ __forceinline__ void dpp_min_u64(unsigned& hi, unsigned& lo) {
  unsigned nhi = (unsigned)dppmov<CTRL>((int)hi);
  unsigned nlo = (unsigned)dppmov<CTRL>((int)lo);
  bool lt = (nhi < hi) || (nhi == hi && nlo < lo);
  hi = lt ? nhi : hi;
  lo = lt ? nlo : lo;
}
template <int CTRL>
__device__ __forceinline__ void dpp_max_u64(unsigned& hi, unsigned& lo) {
  unsigned nhi = (unsigned)dppmov<CTRL>((int)hi);
  unsigned nlo = (unsigned)dppmov<CTRL>((int)lo);
  bool gt = (nhi > hi) || (nhi == hi && nlo > lo);
  hi = gt ? nhi : hi;
  lo = gt ? nlo : lo;
}
template <int CTRL>
__device__ __forceinline__ void dpp_fmax(float& m) {
  m = fmaxf(m, __int_as_float(dppmov<CTRL>(__float_as_int(m))));
}
template <int CTRL>
__device__ __forceinline__ void dpp_umin(unsigned& v) {
  unsigned o = (unsigned)dppmov<CTRL>((int)v);
  v = (o < v) ? o : v;
}

#define XSTR 104
__global__ __launch_bounds__(512, 2) void fused_kernel(
    const float* __restrict__ xyz, const float* __restrict__ points,
    const float* __restrict__ w0, const float* __restrict__ cb0, const float* __restrict__ g0,
    const float* __restrict__ b0, const float* __restrict__ m0, const float* __restrict__ v0,
    const float* __restrict__ w1, const float* __restrict__ cb1, const float* __restrict__ g1,
    const float* __restrict__ b1, const float* __restrict__ m1, const float* __restrict__ v1,
    const float* __restrict__ w2, const float* __restrict__ cb2, const float* __restrict__ g2,
    const float* __restrict__ b2, const float* __restrict__ m2, const float* __restrict__ v2,
    char* __restrict__ wsb, float* __restrict__ newxyz, float* __restrict__ outp) {
  struct FpsSh {
    float4 sxyz4[NPTS];                       // 64 KB
    float4 centL[NS];                         // 16 KB
    unsigned long long part[2][8];
  };
  struct WorkerSh {
    short Wlds[WFRAG_ELEMS];                  // 36 KB
    union {
      unsigned long long slist[2][4096];      // 64 KB (knn phase)
      short X[8][32 * XSTR];                  // 52 KB (mlp phase)
    } u;
    unsigned long long wl[2][128];
    int nnL[8][KNB];
    float biasL[256];
    float pubq[8][3];
    unsigned gshare;
  };
  __shared__ union { FpsSh f; WorkerSh w; } sh;

  const int t = threadIdx.x;
  const int lane = t & 63;
  const int wave = t >> 6;
  unsigned* flagp = (unsigned*)(wsb + FLAG_OFF_B);
  unsigned* cntp  = (unsigned*)(wsb + CNT_OFF_B);
  float* pubC = (float*)(wsb + PUBC_OFF_B);

  if (blockIdx.x < NB) {
    // ================= FPS (r10 config: 8 waves x 8 pts; slot-read DPP merge) ==========
    const int b = blockIdx.x;
    const float* xb = xyz + (size_t)b * NPTS * 3;
    float* outb = newxyz + (size_t)b * NS * 3;

    for (int i = t; i < NPTS; i += 512)
      sh.f.sxyz4[i] = make_float4(xb[i * 3 + 0], xb[i * 3 + 1], xb[i * 3 + 2], 0.f);

    float px[8], py[8], pz[8], dist[8];
#pragma unroll
    for (int j = 0; j < 8; ++j) {
      int n = t + 512 * j;
      px[j] = xb[n * 3 + 0];
      py[j] = xb[n * 3 + 1];
      pz[j] = xb[n * 3 + 2];
      dist[j] = 1e10f;
    }
    __syncthreads();
    float cx = sh.f.sxyz4[0].x, cy = sh.f.sxyz4[0].y, cz = sh.f.sxyz4[0].z;
    if (t == 0) sh.f.centL[0] = sh.f.sxyz4[0];

    for (int it = 1; it < NS; ++it) {
      const int buf = it & 1;
      float dm[8];
#pragma unroll
      for (int j = 0; j < 8; ++j) {
        // exact replication of sum((xyz - c)**2, -1): no FMA contraction
        float dx = __fsub_rn(px[j], cx);
        float dy = __fsub_rn(py[j], cy);
        float dz = __fsub_rn(pz[j], cz);
        float d  = __fadd_rn(__fadd_rn(__fmul_rn(dx, dx), __fmul_rn(dy, dy)), __fmul_rn(dz, dz));
        float v  = fminf(dist[j], d);
        dist[j] = v;
        dm[j] = v;
      }
      // lane max (7-instr tree), then 6-stage f32 DPP max -> lane 63
      float m = fmaxf(fmaxf(fmaxf(dm[0], dm[1]), fmaxf(dm[2], dm[3])),
                      fmaxf(fmaxf(dm[4], dm[5]), fmaxf(dm[6], dm[7])));
      dpp_fmax<0xB1>(m);  dpp_fmax<0x4E>(m);  dpp_fmax<0x141>(m);
      dpp_fmax<0x140>(m); dpp_fmax<0x142>(m); dpp_fmax<0x143>(m);
      float M = __int_as_float(__builtin_amdgcn_readlane(__float_as_int(m), 63));
      // min index with dm == M (descending j overwrite keeps lowest idx per lane)
      unsigned idxl = 0xFFFFFFFFu;
#pragma unroll
      for (int j = 7; j >= 0; --j) idxl = (dm[j] == M) ? (unsigned)(t + 512 * j) : idxl;
      dpp_umin<0xB1>(idxl);  dpp_umin<0x4E>(idxl);  dpp_umin<0x141>(idxl);
      dpp_umin<0x140>(idxl); dpp_umin<0x142>(idxl); dpp_umin<0x143>(idxl);
      if (lane == 63)
        sh.f.part[buf][wave] = ((unsigned long long)__float_as_uint(M) << 32) | (unsigned)(~idxl);
      __syncthreads();
      // merge 8 wave partials: slot read + 3-stage DPP u64 max (every lane gets winner)
      unsigned long long k0 = sh.f.part[buf][lane & 7];
      unsigned khi = (unsigned)(k0 >> 32), klo = (unsigned)k0;
      dpp_max_u64<0xB1>(khi, klo);    // xor1
      dpp_max_u64<0x4E>(khi, klo);    // xor2
      dpp_max_u64<0x141>(khi, klo);   // half-mirror: combines the two 4-groups
      int bi = (int)(~klo) & 4095;
      float4 c4 = sh.f.sxyz4[bi];
      cx = c4.x; cy = c4.y; cz = c4.z;
      if (t == 0) sh.f.centL[it] = c4;
      // publish: release flag for PREVIOUS chunk first (vmcnt already drained -> no stall),
      // then store this chunk's centroids.
      if ((it & 31) == 31 && wave == 0) {
        if (lane == 0)
          __hip_atomic_store(&flagp[b], (unsigned)(it - 31), __ATOMIC_RELEASE, __HIP_MEMORY_SCOPE_AGENT);
        if (lane < 32) {
          int ci = it - 31 + lane;
          float4 cc = sh.f.centL[ci];
          float* dst = pubC + ((size_t)b * NS + ci) * 3;
          __hip_atomic_store(dst + 0, cc.x, __ATOMIC_RELAXED, __HIP_MEMORY_SCOPE_AGENT);
          __hip_atomic_store(dst + 1, cc.y, __ATOMIC_RELAXED, __HIP_MEMORY_SCOPE_AGENT);
          __hip_atomic_store(dst + 2, cc.z, __ATOMIC_RELAXED, __HIP_MEMORY_SCOPE_AGENT);
        }
      }
    }
    // final flag (waits on last chunk's stores once)
    if (wave == 0 && lane == 0)
      __hip_atomic_store(&flagp[b], (unsigned)NS, __ATOMIC_RELEASE, __HIP_MEMORY_SCOPE_AGENT);
    __syncthreads();
    const float* cf = (const float*)sh.f.centL;
    for (int i = t; i < NS * 3; i += 512) {
      int p = i / 3, c = i - p * 3;
      outb[i] = cf[p * 4 + c];
    }
  }

  // ================= worker phase (worker blocks immediately; FPS blocks after FPS) =========
  __syncthreads();
  // compute BN-folded bf16 weight fragments + biases directly into LDS (in wait shadow)
  for (int i = t; i < WFRAG_ELEMS; i += 512) {
    int g = i >> 9, ln = (i >> 3) & 63, j = i & 7;
    int l, nt, s;
    if (g < 12)      { l = 0; nt = g / 3;  s = g % 3; }
    else if (g < 20) { l = 1; int gg = g - 12; nt = gg >> 1; s = gg & 1; }
    else             { l = 2; int gg = g - 20; nt = gg >> 1; s = gg & 1; }
    int n = nt * 16 + (ln & 15);
    int k = s * 32 + ((ln >> 4) << 3) + j;
    float val = 0.f;
    if (l == 0) { if (k < 67) val = w0[n * 67 + k] * (g0[n] / sqrtf(v0[n] + 1e-5f)); }
    else if (l == 1) { val = w1[n * 64 + k] * (g1[n] / sqrtf(v1[n] + 1e-5f)); }
    else { val = w2[n * 64 + k] * (g2[n] / sqrtf(v2[n] + 1e-5f)); }
    sh.w.Wlds[i] = f2bf(val);
  }
  if (t < 256) {
    int o = t;
    float bv;
    if (o < 64)       { float sc = g0[o] / sqrtf(v0[o] + 1e-5f); bv = (cb0[o] - m0[o]) * sc + b0[o]; }
    else if (o < 128) { int c = o - 64;  float sc = g1[c] / sqrtf(v1[c] + 1e-5f); bv = (cb1[c] - m1[c]) * sc + b1[c]; }
    else              { int c = o - 128; float sc = g2[c] / sqrtf(v2[c] + 1e-5f); bv = (cb2[c] - m2[c]) * sc + b2[c]; }
    sh.w.biasL[o] = bv;
  }
  const int team = t >> 8, tt = t & 255;

  for (;;) {
    __syncthreads();                              // LDS reuse + gshare WAR
    if (t == 0) sh.w.gshare = atomicAdd(cntp, 1u);
    __syncthreads();
    unsigned g = sh.w.gshare;
    if (g >= NGROUPS) break;
    const int b = (int)(g & 15u);
    const int s0 = (int)(g >> 4) << 3;

    if (t == 0) {
      unsigned need = (unsigned)(s0 + 8);
      for (;;) {
        unsigned f = __hip_atomic_load(&flagp[b], __ATOMIC_ACQUIRE, __HIP_MEMORY_SCOPE_AGENT);
        if (f >= need) break;
        __builtin_amdgcn_s_sleep(8);
      }
    }
    __syncthreads();
    if (t < 24)
      sh.w.pubq[t / 3][t % 3] = __hip_atomic_load(
          &pubC[((size_t)b * NS + s0 + t / 3) * 3 + (t % 3)],
          __ATOMIC_RELAXED, __HIP_MEMORY_SCOPE_AGENT);
    __syncthreads();

    const float* xb = xyz + (size_t)b * NPTS * 3;

    // ---- knn: 2 teams x 4 sequential queries (verified algorithm) ----
    for (int sub = 0; sub < 4; ++sub) {
      const int qi = team * 4 + sub;
      float qx = sh.w.pubq[qi][0], qy = sh.w.pubq[qi][1], qz = sh.w.pubq[qi][2];
      float s2 = __fadd_rn(__fadd_rn(__fmul_rn(qx, qx), __fmul_rn(qy, qy)), __fmul_rn(qz, qz));
      unsigned long long key[16];
#pragma unroll
      for (int j = 0; j < 16; ++j) {
        int n = tt + 256 * j;
        float px = xb[n * 3], py = xb[n * 3 + 1], pz = xb[n * 3 + 2];
        float n2 = __fadd_rn(__fadd_rn(__fmul_rn(px, px), __fmul_rn(py, py)), __fmul_rn(pz, pz));
        float dt = __fadd_rn(__fadd_rn(__fmul_rn(qx, px), __fmul_rn(qy, py)), __fmul_rn(qz, pz));
        float d  = __fadd_rn(__fsub_rn(s2, __fmul_rn(2.0f, dt)), n2);
        unsigned u = __float_as_uint(d);
        u ^= (0x80000000u | (unsigned)((int)u >> 31));   // monotone float->uint
        key[j] = ((unsigned long long)u << 32) | (unsigned)n;
      }
      // per-thread Batcher odd-even mergesort of 16 keys (ascending)
#pragma unroll
      for (int p = 1; p < 16; p <<= 1) {
#pragma unroll
        for (int k = p; k >= 1; k >>= 1) {
#pragma unroll
          for (int j = k % p; j + k < 16; j += 2 * k) {
#pragma unroll
            for (int i = 0; i < k; ++i) {
              if (i + j + k < 16 && (i + j) / (2 * p) == (i + j + k) / (2 * p)) {
                unsigned long long ka = key[i + j], kb = key[i + j + k];
                unsigned long long mn = ka < kb ? ka : kb;
                unsigned long long mx = ka < kb ? kb : ka;
                key[i + j] = mn; key[i + j + k] = mx;
              }
            }
          }
        }
      }
#pragma unroll
      for (int i = 0; i < 16; ++i) sh.w.u.slist[team][i * 256 + tt] = key[i];

      // per-wave top-32 via head-pointer tournament
      unsigned long long head = key[0];
      unsigned long long nxt  = key[1];
      unsigned p = 1;
      for (int r = 0; r < KNB; ++r) {
        unsigned hi = (unsigned)(head >> 32), lo = (unsigned)head;
        dpp_min_u64<0xB1>(hi, lo);
        dpp_min_u64<0x4E>(hi, lo);
        dpp_min_u64<0x141>(hi, lo);
        dpp_min_u64<0x140>(hi, lo);
        dpp_min_u64<0x142>(hi, lo);
        dpp_min_u64<0x143>(hi, lo);
        unsigned whi = (unsigned)__builtin_amdgcn_readlane((int)hi, 63);
        unsigned wlo = (unsigned)__builtin_amdgcn_readlane((int)lo, 63);
        unsigned long long wkey = ((unsigned long long)whi << 32) | wlo;
        if ((tt & 63) == 0) sh.w.wl[team][(tt >> 6) * 32 + r] = wkey;
        if (head == wkey) {
          head = (p < 16) ? nxt : 0xFFFFFFFFFFFFFFFFull;
          unsigned pn = p + 1;
          nxt = sh.w.u.slist[team][(pn < 16 ? pn : 15) * 256 + tt];
          p = pn;
        }
      }
      __syncthreads();
      if (tt < 128) {                    // rank-merge (keys unique)
        unsigned long long mykey = sh.w.wl[team][tt];
        int gr = 0;
#pragma unroll 8
        for (int i = 0; i < 128; ++i) gr += (sh.w.wl[team][i] < mykey) ? 1 : 0;
        if (gr < KNB) sh.w.nnL[qi][gr] = (int)(mykey & 0xFFFFFFFFull);
      }
      __syncthreads();
    }

    // ---- mlp: 8 waves x 1 query (verified MFMA path) ----
    {
      const int qi = wave;
      const int s = s0 + qi;
      float qx = sh.w.pubq[qi][0], qy = sh.w.pubq[qi][1], qz = sh.w.pubq[qi][2];
      const float* pb = points + (size_t)b * NPTS * CPTS;
      const float* bias = sh.w.biasL;
      short* X = sh.w.u.X[qi];

      {
        int r = lane & 31, half = lane >> 5;
        int idx = sh.w.nnL[qi][r];
        const float* prow = pb + (size_t)idx * CPTS;
#pragma unroll
        for (int i = 0; i < 48; ++i) {
          int c = half * 48 + i;
          float v;
          if (c < 3) {
            float qc = (c == 0) ? qx : ((c == 1) ? qy : qz);
            v = __fsub_rn(xb[idx * 3 + c], qc);
          } else if (c < 67) {
            v = prow[c - 3];
          } else {
            v = 0.f;
          }
          X[r * XSTR + c] = f2bf(v);
        }
      }

      const int ml = lane & 15, quad = lane >> 4;
      const short8* Wf = (const short8*)sh.w.Wlds;

      // layer 0: M32 K96 N64
      short8 a0[2][3];
#pragma unroll
      for (int m2 = 0; m2 < 2; ++m2)
#pragma unroll
        for (int s3 = 0; s3 < 3; ++s3)
          a0[m2][s3] = *(const short8*)&X[(m2 * 16 + ml) * XSTR + s3 * 32 + quad * 8];
      f32x4 acc0[2][4];
#pragma unroll
      for (int m2 = 0; m2 < 2; ++m2)
#pragma unroll
        for (int nt = 0; nt < 4; ++nt) {
          f32x4 c = {0.f, 0.f, 0.f, 0.f};
#pragma unroll
          for (int s3 = 0; s3 < 3; ++s3)
            c = __builtin_amdgcn_mfma_f32_16x16x32_bf16(a0[m2][s3], Wf[(nt * 3 + s3) * 64 + lane], c, 0, 0, 0);
          acc0[m2][nt] = c;
        }
#pragma unroll
      for (int m2 = 0; m2 < 2; ++m2)
#pragma unroll
        for (int nt = 0; nt < 4; ++nt) {
          int ch = nt * 16 + ml;
          float bv = bias[ch];
#pragma unroll
          for (int r4 = 0; r4 < 4; ++r4) {
            float y = fmaxf(acc0[m2][nt][r4] + bv, 0.f);
            int m = quad * 4 + r4;
            int sK = ch >> 5, qq = (ch >> 3) & 3, jj = ch & 7;
            X[((m2 * 2 + sK) * 64 + qq * 16 + m) * 8 + jj] = f2bf(y);
          }
        }

      // layer 1: M32 K64 N64
      short8 a1[2][2];
#pragma unroll
      for (int m2 = 0; m2 < 2; ++m2)
#pragma unroll
        for (int sK = 0; sK < 2; ++sK)
          a1[m2][sK] = *(const short8*)&X[((m2 * 2 + sK) * 64 + lane) * 8];
      f32x4 acc1[2][4];
#pragma unroll
      for (int m2 = 0; m2 < 2; ++m2)
#pragma unroll
        for (int nt = 0; nt < 4; ++nt) {
          f32x4 c = {0.f, 0.f, 0.f, 0.f};
#pragma unroll
          for (int sK = 0; sK < 2; ++sK)
            c = __builtin_amdgcn_mfma_f32_16x16x32_bf16(a1[m2][sK], Wf[(12 + nt * 2 + sK) * 64 + lane], c, 0, 0, 0);
          acc1[m2][nt] = c;
        }
#pragma unroll
      for (int m2 = 0; m2 < 2; ++m2)
#pragma unroll
        for (int nt = 0; nt < 4; ++nt) {
          int ch = nt * 16 + ml;
          float bv = bias[64 + ch];
#pragma unroll
          for (int r4 = 0; r4 < 4; ++r4) {
            float y = fmaxf(acc1[m2][nt][r4] + bv, 0.f);
            int m = quad * 4 + r4;
            int sK = ch >> 5, qq = (ch >> 3) & 3, jj = ch & 7;
            X[((m2 * 2 + sK) * 64 + qq * 16 + m) * 8 + jj] = f2bf(y);
          }
        }

      // layer 2: M32 K64 N128 + maxpool
      short8 a2[2][2];
#pragma unroll
      for (int m2 = 0; m2 < 2; ++m2)
#pragma unroll
        for (int sK = 0; sK < 2; ++sK)
          a2[m2][sK] = *(const short8*)&X[((m2 * 2 + sK) * 64 + lane) * 8];
#pragma unroll
      for (int nt = 0; nt < 8; ++nt) {
        f32x4 c0 = {0.f, 0.f, 0.f, 0.f}, c1 = {0.f, 0.f, 0.f, 0.f};
        short8 w0f = Wf[(20 + nt * 2 + 0) * 64 + lane];
        short8 w1f = Wf[(20 + nt * 2 + 1) * 64 + lane];
        c0 = __builtin_amdgcn_mfma_f32_16x16x32_bf16(a2[0][0], w0f, c0, 0, 0, 0);
        c0 = __builtin_amdgcn_mfma_f32_16x16x32_bf16(a2[0][1], w1f, c0, 0, 0, 0);
        c1 = __builtin_amdgcn_mfma_f32_16x16x32_bf16(a2[1][0], w0f, c1, 0, 0, 0);
        c1 = __builtin_amdgcn_mfma_f32_16x16x32_bf16(a2[1][1], w1f, c1, 0, 0, 0);
        float bv = bias[128 + nt * 16 + ml];
        float m = -1.f;
#pragma unroll
        for (int r4 = 0; r4 < 4; ++r4) {
          m = fmaxf(m, fmaxf(c0[r4] + bv, 0.f));
          m = fmaxf(m, fmaxf(c1[r4] + bv, 0.f));
        }
        m = fmaxf(m, __shfl_xor(m, 16, 64));
        m = fmaxf(m, __shfl_xor(m, 32, 64));
        if (lane < 16) outp[((size_t)b * 128 + nt * 16 + lane) * NS + s] = m;
      }
    }
  }
}

extern "C" void kernel_launch(void* const* d_in, const int* in_sizes, int n_in,
                              void* d_out, int out_size, void* d_ws, size_t ws_size,
                              hipStream_t stream) {
  const float* xyz    = (const float*)d_in[0];
  const float* points = (const float*)d_in[1];
  const float* w0  = (const float*)d_in[2];
  const float* cb0 = (const float*)d_in[3];
  const float* g0  = (const float*)d_in[4];
  const float* b0  = (const float*)d_in[5];
  const float* m0  = (const float*)d_in[6];
  const float* v0  = (const float*)d_in[7];
  const float* w1  = (const float*)d_in[8];
  const float* cb1 = (const float*)d_in[9];
  const float* g1  = (const float*)d_in[10];
  const float* b1  = (const float*)d_in[11];
  const float* m1  = (const float*)d_in[12];
  const float* v1  = (const float*)d_in[13];
  const float* w2  = (const float*)d_in[14];
  const float* cb2 = (const float*)d_in[15];
  const float* g2  = (const float*)d_in[16];
  const float* b2  = (const float*)d_in[17];
  const float* m2  = (const float*)d_in[18];
  const float* v2  = (const float*)d_in[19];

  char*  wsb    = (char*)d_ws;
  float* newxyz = (float*)d_out;                       // output 0: [16,1024,3]
  float* outp   = (float*)d_out + (size_t)NB * NS * 3; // output 1: [16,128,1024]

  hipMemsetAsync(wsb, 0, 128, stream);   // flags + counter
  fused_kernel<<<256, 512, 0, stream>>>(
      xyz, points, w0, cb0, g0, b0, m0, v0, w1, cb1, g1, b1, m1, v1,
      w2, cb2, g2, b2, m2, v2, wsb, newxyz, outp);
}